// Round 3
// baseline (256.499 us; speedup 1.0000x reference)
//
#include <hip/hip_runtime.h>
#include <hip/hip_bf16.h>
#include <stdint.h>

// QuantizedLinear: out[16,11008] = x[16,4096] @ ((W - zp)*scale)^T
// W arrives as int32 (harness: integer -> const int*) = 180 MB -> HBM-bound,
// floor ~29 us. v3: wave-private double-buffered global_load_lds staging of W
// (4-8 KB in flight per wave, no barriers in K-loop) + XOR-swizzled LDS layout
// for conflict-free ds_read_b128 fragment reads + i8 MFMA with hi/lo x planes.

#define M_TOK 16
#define K_DIM 4096
#define N_OUT 11008

typedef int v4i __attribute__((ext_vector_type(4)));

#define GLOAD_LDS16(g, l)                                               \
  __builtin_amdgcn_global_load_lds(                                     \
      (const __attribute__((address_space(1))) void*)(g),               \
      (__attribute__((address_space(3))) void*)(l), 16, 0, 0)

// ---------------- Kernel 1: per-token quantization of x ----------------
// x ~= s1 * (xh + xl/256), 15-bit effective precision. PASSED R2 — unchanged.
__global__ __launch_bounds__(256) void quant_x_kernel(
    const float* __restrict__ x, int8_t* __restrict__ xh,
    int8_t* __restrict__ xl, float* __restrict__ s1_out,
    float* __restrict__ sumx_out) {
  const int t = blockIdx.x;
  const int tid = threadIdx.x;
  const float4* xv = (const float4*)(x + (long)t * K_DIM) + tid * 4;

  float vals[16];
  float m = 0.0f, s = 0.0f;
#pragma unroll
  for (int j = 0; j < 4; ++j) {
    float4 f = xv[j];
    vals[j * 4 + 0] = f.x; vals[j * 4 + 1] = f.y;
    vals[j * 4 + 2] = f.z; vals[j * 4 + 3] = f.w;
    m = fmaxf(m, fmaxf(fmaxf(fabsf(f.x), fabsf(f.y)),
                       fmaxf(fabsf(f.z), fabsf(f.w))));
    s += f.x + f.y + f.z + f.w;
  }
#pragma unroll
  for (int off = 32; off > 0; off >>= 1) {
    m = fmaxf(m, __shfl_xor(m, off));
    s += __shfl_xor(s, off);
  }
  __shared__ float lm[4], ls[4];
  const int w = tid >> 6;
  if ((tid & 63) == 0) { lm[w] = m; ls[w] = s; }
  __syncthreads();
  m = fmaxf(fmaxf(lm[0], lm[1]), fmaxf(lm[2], lm[3]));
  s = ls[0] + ls[1] + ls[2] + ls[3];

  const float s1 = (m > 0.0f) ? (m * (1.0f / 127.0f)) : 1.0f;
  const float inv = 1.0f / s1;
  if (tid == 0) { s1_out[t] = s1; sumx_out[t] = s; }

  int hq[16], lq[16];
#pragma unroll
  for (int j = 0; j < 16; ++j) {
    float xf = vals[j];
    float h = rintf(xf * inv);
    h = fminf(fmaxf(h, -127.0f), 127.0f);
    float resid = xf - h * s1;
    float l = rintf(resid * inv * 256.0f);
    l = fminf(fmaxf(l, -128.0f), 127.0f);
    hq[j] = (int)h;
    lq[j] = (int)l;
  }
  int4 hv, lv;
  int* hp = (int*)&hv;
  int* lp = (int*)&lv;
#pragma unroll
  for (int d = 0; d < 4; ++d) {
    uint32_t hw = 0, lw = 0;
#pragma unroll
    for (int j = 0; j < 4; ++j) {
      hw |= (uint32_t)(hq[d * 4 + j] & 0xff) << (8 * j);
      lw |= (uint32_t)(lq[d * 4 + j] & 0xff) << (8 * j);
    }
    hp[d] = (int)hw;
    lp[d] = (int)lw;
  }
  ((int4*)xh)[(long)t * 256 + tid] = hv;
  ((int4*)xl)[(long)t * 256 + tid] = lv;
}

// ---------------- Kernel 2: weight-streaming i8 MFMA GEMM ----------------
// 688 blocks x 256 thr. Block owns 16 W rows; wave w owns k-slice
// [s*256 + w*64, +64) int32 per stage s (16 stages). Wave-private LDS double
// buffer, staged with 4x global_load_lds(16B) per stage (contiguous 256 B per
// 16-lane group). LDS slot layout XOR-swizzled: slot(row,q) at row*16 +
// (q^(row&7)) -> conflict-free b128 reads. No __syncthreads in K-loop.
__global__ __launch_bounds__(256) void qgemm_kernel(
    const int* __restrict__ W, const int8_t* __restrict__ xh,
    const int8_t* __restrict__ xl, const float* __restrict__ s1,
    const float* __restrict__ sumx, const float* __restrict__ scale_p,
    const int* __restrict__ zp_p, float* __restrict__ out) {
  const int tid = threadIdx.x;
  const int lane = tid & 63;
  const int w = tid >> 6;          // wave id = K split
  const int obase = blockIdx.x * 16;
  const int n = lane & 15;         // B: W-row within tile / A: token
  const int g = lane >> 4;         // k sub-group within 64-k chunk

  __shared__ int wlds[2][4][1024]; // [buf][wave][16 rows * 64 int32] = 32 KB

  // Staging source pointers, instr j (j=0..3): lane loads row obase+j*4+g,
  // int32 offset w*64 + (n ^ g ^ ((j&1)<<2))*4  (+ s*256 per stage).
  const int* gj0 = W + (long)(obase + 0 + g) * K_DIM + w * 64 + ((n ^ g) ^ 0) * 4;
  const int* gj1 = W + (long)(obase + 4 + g) * K_DIM + w * 64 + ((n ^ g) ^ 4) * 4;
  const int* gj2 = W + (long)(obase + 8 + g) * K_DIM + w * 64 + ((n ^ g) ^ 0) * 4;
  const int* gj3 = W + (long)(obase + 12 + g) * K_DIM + w * 64 + ((n ^ g) ^ 4) * 4;

  // ds_read slot indices: read t wants (row n, slot q=g*4+t), stored at
  // n*16 + (q ^ (n&7)); int32 index = that*4.
  const int Q0 = (g * 4) ^ (n & 7);
  const int r0 = n * 64 + ((Q0 ^ 0)) * 4;
  const int r1 = n * 64 + ((Q0 ^ 1)) * 4;
  const int r2 = n * 64 + ((Q0 ^ 2)) * 4;
  const int r3 = n * 64 + ((Q0 ^ 3)) * 4;

  const v4i* Ah = (const v4i*)(xh + (long)n * K_DIM + w * 64 + g * 16);
  const v4i* Al = (const v4i*)(xl + (long)n * K_DIM + w * 64 + g * 16);

  v4i accH = {0, 0, 0, 0};
  v4i accL = {0, 0, 0, 0};

  // Prologue: stage 0 -> buf 0
  GLOAD_LDS16(gj0, &wlds[0][w][0]);
  GLOAD_LDS16(gj1, &wlds[0][w][256]);
  GLOAD_LDS16(gj2, &wlds[0][w][512]);
  GLOAD_LDS16(gj3, &wlds[0][w][768]);

#pragma unroll
  for (int s = 0; s < 16; ++s) {
    const int b = s & 1;
    if (s + 1 < 16) {  // prefetch next stage into other buffer
      const int soff = (s + 1) * 256;
      GLOAD_LDS16(gj0 + soff, &wlds[b ^ 1][w][0]);
      GLOAD_LDS16(gj1 + soff, &wlds[b ^ 1][w][256]);
      GLOAD_LDS16(gj2 + soff, &wlds[b ^ 1][w][512]);
      GLOAD_LDS16(gj3 + soff, &wlds[b ^ 1][w][768]);
    }
    v4i ah = Ah[s * 16];
    v4i al = Al[s * 16];

    v4i q0 = *(const v4i*)&wlds[b][w][r0];
    v4i q1 = *(const v4i*)&wlds[b][w][r1];
    v4i q2 = *(const v4i*)&wlds[b][w][r2];
    v4i q3 = *(const v4i*)&wlds[b][w][r3];

    v4i bf;
    bf[0] = (int)(((uint32_t)q0[0] & 0xffu) | (((uint32_t)q0[1] & 0xffu) << 8) |
                  (((uint32_t)q0[2] & 0xffu) << 16) | ((uint32_t)q0[3] << 24));
    bf[1] = (int)(((uint32_t)q1[0] & 0xffu) | (((uint32_t)q1[1] & 0xffu) << 8) |
                  (((uint32_t)q1[2] & 0xffu) << 16) | ((uint32_t)q1[3] << 24));
    bf[2] = (int)(((uint32_t)q2[0] & 0xffu) | (((uint32_t)q2[1] & 0xffu) << 8) |
                  (((uint32_t)q2[2] & 0xffu) << 16) | ((uint32_t)q2[3] << 24));
    bf[3] = (int)(((uint32_t)q3[0] & 0xffu) | (((uint32_t)q3[1] & 0xffu) << 8) |
                  (((uint32_t)q3[2] & 0xffu) << 16) | ((uint32_t)q3[3] << 24));

    accH = __builtin_amdgcn_mfma_i32_16x16x64_i8(ah, bf, accH, 0, 0, 0);
    accL = __builtin_amdgcn_mfma_i32_16x16x64_i8(al, bf, accL, 0, 0, 0);
  }

  // Epilogue: 4-way K reduction via LDS.
  // C layout (16x16): col = lane&15 (=o), row = (lane>>4)*4 + reg (=token)
  __shared__ float red[4][16 * 17];
#pragma unroll
  for (int r = 0; r < 4; ++r) {
    float f = (float)accH[r] + (float)accL[r] * (1.0f / 256.0f);
    int t = g * 4 + r;
    red[w][t * 17 + n] = f;
  }
  __syncthreads();

  const int t = tid >> 4;
  const int col = tid & 15;
  float sum = red[0][t * 17 + col] + red[1][t * 17 + col] +
              red[2][t * 17 + col] + red[3][t * 17 + col];
  const float sc = scale_p[0];
  const float zp = (float)zp_p[0];
  float o = sc * (s1[t] * sum) - sc * zp * sumx[t];
  out[(long)t * N_OUT + obase + col] = o;
}

extern "C" void kernel_launch(void* const* d_in, const int* in_sizes, int n_in,
                              void* d_out, int out_size, void* d_ws,
                              size_t ws_size, hipStream_t stream) {
  const float* x = (const float*)d_in[0];
  const int* Wq = (const int*)d_in[1];  // integer inputs come as int32
  const float* scale_p = (const float*)d_in[2];
  const int* zp_p = (const int*)d_in[3];
  float* out = (float*)d_out;

  int8_t* xh = (int8_t*)d_ws;
  int8_t* xl = xh + (long)M_TOK * K_DIM;
  float* s1 = (float*)(xl + (long)M_TOK * K_DIM);
  float* sumx = s1 + M_TOK;

  quant_x_kernel<<<M_TOK, 256, 0, stream>>>(x, xh, xl, s1, sumx);
  qgemm_kernel<<<N_OUT / 16, 256, 0, stream>>>(Wq, xh, xl, s1, sumx, scale_p,
                                               zp_p, out);
}